// Round 8
// baseline (212.025 us; speedup 1.0000x reference)
//
#include <hip/hip_runtime.h>

// Problem constants (from reference)
#define DIM_IN   2048
#define FEAT     128
#define KP1      16385      // NCE_N + 1
#define NDATA    100000
#define BATCH    64
#define NBT      256        // bank rows per gemm block (2 subtiles of 128)
#define NTIL     ((NDATA + NBT - 1) / NBT)   // 391
#define GCH      32         // k-chunks per (side,b) in gather kernel
#define LCH      8          // chunks in loss kernel

constexpr float NCE_T_INV = 1.0f / 0.07f;
constexpr float M_CONST   = 16384.0f / 100000.0f;   // NCE_N / N_DATA
constexpr float EPS_C     = 1e-7f;

typedef short bf16x8 __attribute__((ext_vector_type(8)));   // 8 bf16 = 4 VGPR
typedef float f32x4  __attribute__((ext_vector_type(4)));   // MFMA acc

// vplanes global layout (bytes), written by embed, DMA'd linearly by gemm:
//   plane(hi=0,lo=1)*34816 + side*17408 + anchor*272 + k*2
#define VP_PLANE 34816
#define VP_SIDE  17408
#define VP_ROW   272

// ---------------------------------------------------------------------------
// Kernel 1: h = l2norm(feat @ w.T + b), emitted as SPLIT-bf16 planes.
// 1024 threads (16 waves): verified round 5.
// Block 0 additionally zeroes z[128] and out.
// ---------------------------------------------------------------------------
__global__ void __launch_bounds__(1024) embed_kernel(
    const float* __restrict__ feat_s, const float* __restrict__ feat_t,
    const float* __restrict__ w_s, const float* __restrict__ b_s,
    const float* __restrict__ w_t, const float* __restrict__ b_t,
    char* __restrict__ vplanes, float* __restrict__ z_zero,
    float* __restrict__ out_zero)
{
    const int blk  = blockIdx.x;      // side*64 + b
    const int side = blk >> 6;
    const int b    = blk & 63;
    const float* feat = (side == 0 ? feat_s : feat_t) + (size_t)b * DIM_IN;
    const float* w    = (side == 0 ? w_s : w_t);
    const float* bias = (side == 0 ? b_s : b_t);

    __shared__ float sfeat[DIM_IN];
    __shared__ float pre[FEAT];
    __shared__ float wsum[2];

    const int t = threadIdx.x;
    if (blk == 0) {                   // fold the memsets into this launch
        if (t < 128) z_zero[t] = 0.f;
        else if (t == 128) out_zero[0] = 0.f;
    }
    {   // coalesced float4 stage of the feat row (8 KB, 512 float4)
        const float4* f4 = (const float4*)feat;
        float4* s4 = (float4*)sfeat;
        if (t < 512) s4[t] = f4[t];
    }
    __syncthreads();

    const int wv = t >> 6, ln = t & 63;   // 16 waves
    const float4* w4  = (const float4*)w;
    const float4* sf4 = (const float4*)sfeat;
#pragma unroll 2
    for (int i = 0; i < 8; ++i) {         // d = wv + 16*i: 8 iters/wave
        const int d = wv + i * 16;
        float s = 0.f;
#pragma unroll
        for (int seg = 0; seg < 8; ++seg) {  // 512 float4 per row / 64 lanes
            float4 a = w4[d * (DIM_IN / 4) + seg * 64 + ln];
            float4 f = sf4[seg * 64 + ln];
            s += a.x * f.x + a.y * f.y + a.z * f.z + a.w * f.w;
        }
#pragma unroll
        for (int o = 32; o > 0; o >>= 1) s += __shfl_xor(s, o, 64);
        if (ln == 0) pre[d] = s;
    }
    __syncthreads();

    if (t < 128) {
        float p = pre[t] + bias[t];
        pre[t] = p;
        float sq = p * p;
#pragma unroll
        for (int o = 32; o > 0; o >>= 1) sq += __shfl_xor(sq, o, 64);
        if ((t & 63) == 0) wsum[t >> 6] = sq;
    }
    __syncthreads();
    if (t < 128) {
        float inv_norm = 1.0f / sqrtf(wsum[0] + wsum[1]);
        float x = pre[t] * inv_norm;
        unsigned int u = __float_as_uint(x);
        unsigned short h = (unsigned short)(u >> 16);
        float hf = __uint_as_float(u & 0xffff0000u);
        float lr = x - hf;                         // exact in fp32
        unsigned short l = (unsigned short)(__float_as_uint(lr) >> 16);
        const size_t off = (size_t)side * VP_SIDE + (size_t)b * VP_ROW + t * 2;
        *(unsigned short*)(vplanes + off)            = h;
        *(unsigned short*)(vplanes + VP_PLANE + off) = l;
    }
}

// ---------------------------------------------------------------------------
// Kernel 2 (PIPELINED): E[sb][n] = exp(dot(bank[n], v[sb])/T).
// Round-7 post-mortem: VGPR_Count=56 proves the compiler SANK the up-front
// B burst to per-chunk use points (32 VGPR of bq can't fit in 56) -- B loads
// still dribbled, HBM stuck at 2.5 TB/s, MfmaUtil 8.5%.
// FIX: rolling pipeline over 8 chunks (2 subtiles x 4), 4 register slots:
//   prologue issues chunks 0-2 (drained by the one barrier with A);
//   compute(j) first issues chunk j+3's loads, then an
//   asm volatile("" ::: "memory") clobber -- loads cannot sink past a
//   memory clobber, pinning issue ~3 chunks (~1000 cyc) ahead of use.
// NBT=256 rows/block (grid 782): A-LDS amortized over 2 subtiles.
//   - A: vplanes padded-272B rows DMA'd linearly (global_load_lds).
//   - split-precision bf16x3: C = Ah*Bh + Al*Bh + Ah*Bl (absmax 0.0 r4-r7).
//   - C/D: col=lane&15 -> bank row n, row=(lane>>4)*4+reg -> anchor (m89).
// ---------------------------------------------------------------------------
__global__ void __launch_bounds__(512) gemm_exp_kernel(
    const float* __restrict__ mem_v1, const float* __restrict__ mem_v2,
    const char* __restrict__ vplanes, float* __restrict__ E)
{
    // LDS map (bytes): [0,17408) A hi : anchor*272 + k*2 ; [17408,34816) A lo
    __shared__ __align__(16) char lds[34816];

    const int bx   = blockIdx.x;
    const int side = bx & 1;
    const int tile = bx >> 1;
    const int n0   = tile * NBT;
    const float* bank = (side == 0 ? mem_v2 : mem_v1);
    const int t  = threadIdx.x;
    const int wv = t >> 6, ln = t & 63;
    const int lm = ln & 15;           // MFMA lane index: n within 16-group
    const int kb = ln >> 4;           // MFMA k-block (0..3)
    const int nloc = wv * 16 + lm;    // row-within-subtile this lane owns

    // subtile row pointers (clamped loads; stores guarded separately)
    int r0 = n0 + nloc;        if (r0 > NDATA - 1) r0 = NDATA - 1;
    int r1 = n0 + 128 + nloc;  if (r1 > NDATA - 1) r1 = NDATA - 1;
    const float* bs0 = bank + (size_t)r0 * FEAT + kb * 8;
    const float* bs1 = bank + (size_t)r1 * FEAT + kb * 8;

    float4 bq[4][2];                  // rolling slots, slot = j & 3
    // prologue: issue chunks 0,1,2 (subtile 0)
#pragma unroll
    for (int j = 0; j < 3; ++j) {
        const float4* p = (const float4*)(bs0 + j * 32);
        bq[j][0] = p[0];
        bq[j][1] = p[1];
    }

    // ---- A planes: linear DMA, 34 segments x 1024 B --------------------
    {
        const char* hbase = vplanes + (size_t)side * VP_SIDE;
        const char* lbase = vplanes + VP_PLANE + (size_t)side * VP_SIDE;
        for (int seg = wv; seg < 34; seg += 8) {
            const char* src = (seg < 17 ? hbase + seg * 1024
                                        : lbase + (seg - 17) * 1024) + ln * 16;
            __builtin_amdgcn_global_load_lds(
                (const __attribute__((address_space(1))) void*)src,
                (__attribute__((address_space(3))) void*)(lds + seg * 1024),
                16, 0, 0);
        }
    }

    f32x4 acc[4];
#pragma unroll
    for (int mi = 0; mi < 4; ++mi) acc[mi] = (f32x4){0.f, 0.f, 0.f, 0.f};

    __syncthreads();    // drains A DMA + prologue B chunks (vmcnt 0)

#pragma unroll
    for (int j = 0; j < 8; ++j) {     // chunk stream: subtile = j>>2, c = j&3
        // issue chunk j+3, pinned by memory clobber (can't sink)
        if (j + 3 < 8) {
            const int jj = j + 3;
            const float* p = (jj < 4 ? bs0 : bs1) + (jj & 3) * 32;
            bq[jj & 3][0] = ((const float4*)p)[0];
            bq[jj & 3][1] = ((const float4*)p)[1];
            asm volatile("" ::: "memory");
        }
        const int c = j & 3;
        // convert this chunk's 8 floats -> split hi/lo bf16x8 (static idx)
        const float xs[8] = {bq[j & 3][0].x, bq[j & 3][0].y,
                             bq[j & 3][0].z, bq[j & 3][0].w,
                             bq[j & 3][1].x, bq[j & 3][1].y,
                             bq[j & 3][1].z, bq[j & 3][1].w};
        bf16x8 bh, bl;
#pragma unroll
        for (int jj = 0; jj < 8; ++jj) {
            unsigned int u = __float_as_uint(xs[jj]);
            bh[jj] = (short)(u >> 16);
            float hf = __uint_as_float(u & 0xffff0000u);
            bl[jj] = (short)(__float_as_uint(xs[jj] - hf) >> 16);
        }
        // A fragments
        bf16x8 ah[4], al[4];
#pragma unroll
        for (int mi = 0; mi < 4; ++mi) {
            ah[mi] = *(const bf16x8*)(lds + (mi * 16 + lm) * VP_ROW + c * 64 + kb * 16);
            al[mi] = *(const bf16x8*)(lds + 17408 + (mi * 16 + lm) * VP_ROW + c * 64 + kb * 16);
        }
        // 3-term split-precision MFMA
#pragma unroll
        for (int mi = 0; mi < 4; ++mi) {
            acc[mi] = __builtin_amdgcn_mfma_f32_16x16x32_bf16(ah[mi], bh, acc[mi], 0, 0, 0);
            acc[mi] = __builtin_amdgcn_mfma_f32_16x16x32_bf16(al[mi], bh, acc[mi], 0, 0, 0);
            acc[mi] = __builtin_amdgcn_mfma_f32_16x16x32_bf16(ah[mi], bl, acc[mi], 0, 0, 0);
        }
        // end of subtile: exp + store, reset acc
        if (c == 3) {
            const int nn = n0 + (j >> 2) * 128 + nloc;
            if (nn < NDATA) {
#pragma unroll
                for (int mi = 0; mi < 4; ++mi)
#pragma unroll
                    for (int jj = 0; jj < 4; ++jj) {
                        const int anchor = mi * 16 + kb * 4 + jj;
                        E[(size_t)(side * 64 + anchor) * NDATA + nn] =
                            __expf(acc[mi][jj] * NCE_T_INV);
                    }
            }
            if (j < 7) {
#pragma unroll
                for (int mi = 0; mi < 4; ++mi)
                    acc[mi] = (f32x4){0.f, 0.f, 0.f, 0.f};
            }
        }
    }
}

// ---------------------------------------------------------------------------
// Kernel 3: gather ex = E[sb][idx[b,k]], store compact, accumulate Z[sb].
// GCH 16 -> 32: halves the per-thread dependent random-load chain; 4096
// blocks. blk&127 = sb keeps a given sb's chunks on one XCD.
// ---------------------------------------------------------------------------
__global__ void __launch_bounds__(256) gather_z_kernel(
    const int* __restrict__ sample_idx, const float* __restrict__ E,
    float* __restrict__ ex_out, float* __restrict__ z_out)
{
    const int blk   = blockIdx.x;
    const int chunk = blk >> 7;          // 0..GCH-1
    const int sb    = blk & 127;         // side*64 + b
    const int b     = sb & 63;
    const float* Eb = E + (size_t)sb * NDATA;

    float zp = 0.f;
    for (int k = chunk * 256 + threadIdx.x; k < KP1; k += GCH * 256) {
        const int idx = sample_idx[(size_t)b * KP1 + k];
        const float e = Eb[idx];
        ex_out[(size_t)sb * KP1 + k] = e;
        zp += e;
    }
#pragma unroll
    for (int o = 32; o > 0; o >>= 1) zp += __shfl_xor(zp, o, 64);
    __shared__ float zw[4];
    if ((threadIdx.x & 63) == 0) zw[threadIdx.x >> 6] = zp;
    __syncthreads();
    if (threadIdx.x == 0) atomicAdd(&z_out[sb], zw[0] + zw[1] + zw[2] + zw[3]);
}

// ---------------------------------------------------------------------------
// Kernel 4: loss. Chunks 2 -> 8 (1024 blocks = 4 blocks/CU): the logf loop
// was latency-exposed at 1 block/CU. Z summed in-kernel from the 64 per-sb
// partials of this side; 1024 output atomics total.
// ---------------------------------------------------------------------------
__global__ void __launch_bounds__(256) loss_kernel(
    const float* __restrict__ ex_in, const float* __restrict__ z_in,
    float* __restrict__ out)
{
    const int blk   = blockIdx.x;
    const int chunk = blk >> 7;          // 0..LCH-1
    const int sb    = blk & 127;
    const int side  = sb >> 6;

    __shared__ float zsh;
    if (threadIdx.x < 64) {
        float zv = z_in[side * 64 + threadIdx.x];
#pragma unroll
        for (int o = 32; o > 0; o >>= 1) zv += __shfl_xor(zv, o, 64);
        if (threadIdx.x == 0) zsh = zv;
    }
    __syncthreads();

    const float z  = zsh * ((float)NDATA / (64.0f * (float)KP1));
    const float rz = 1.0f / z;
    const float* ex = ex_in + (size_t)sb * KP1;

    float part = 0.f;
    for (int k = chunk * 256 + threadIdx.x; k < KP1; k += LCH * 256) {
        const float x = ex[k] * rz;
        if (k == 0) part += __logf(x / (x + M_CONST + EPS_C));
        else        part += __logf(M_CONST / (x + M_CONST + EPS_C));
    }
#pragma unroll
    for (int o = 32; o > 0; o >>= 1) part += __shfl_xor(part, o, 64);
    __shared__ float pw[4];
    if ((threadIdx.x & 63) == 0) pw[threadIdx.x >> 6] = part;
    __syncthreads();
    if (threadIdx.x == 0)
        atomicAdd(out, -(pw[0] + pw[1] + pw[2] + pw[3]) * (1.0f / 64.0f));
}

// ---------------------------------------------------------------------------
extern "C" void kernel_launch(void* const* d_in, const int* in_sizes, int n_in,
                              void* d_out, int out_size, void* d_ws, size_t ws_size,
                              hipStream_t stream)
{
    const float* feat_s     = (const float*)d_in[0];
    const float* feat_t     = (const float*)d_in[1];
    /* d_in[2] = idx, unused: sample_idx[:,0] already holds it */
    const int*   sample_idx = (const int*)  d_in[3];
    const float* w_s        = (const float*)d_in[4];
    const float* b_s        = (const float*)d_in[5];
    const float* w_t        = (const float*)d_in[6];
    const float* b_t        = (const float*)d_in[7];
    const float* mem_v1     = (const float*)d_in[8];
    const float* mem_v2     = (const float*)d_in[9];
    float* out = (float*)d_out;

    // Workspace layout:
    //   [z: 128 f32 = 512 B]
    //   [ex: 2*64*16385 f32 = 8.39 MB]   (gather-write -> loss-read)
    //   [vplanes: 69632 B, ALIASES ex]   (embed-write -> gemm-read; lifetimes
    //                                     disjoint: gemm ends before gather)
    //   [E: 128*100000 f32 = 51.2 MB]    (transposed: E[sb][n])
    char*  ws     = (char*)d_ws;
    float* ws_z   = (float*)ws;
    float* ws_ex  = (float*)(ws + 512);
    char*  ws_vp  = (char*)(ws + 512);   // alias of ex region
    float* ws_E   = (float*)(ws + 512 + (size_t)2 * BATCH * KP1 * sizeof(float));

    // z/out zeroing folded into embed_kernel block 0
    embed_kernel<<<2 * BATCH, 1024, 0, stream>>>(feat_s, feat_t, w_s, b_s, w_t, b_t,
                                                 ws_vp, ws_z, out);
    gemm_exp_kernel<<<2 * NTIL, 512, 0, stream>>>(mem_v1, mem_v2, ws_vp, ws_E);
    gather_z_kernel<<<2 * BATCH * GCH, 256, 0, stream>>>(sample_idx, ws_E, ws_ex, ws_z);
    loss_kernel<<<2 * BATCH * LCH, 256, 0, stream>>>(ws_ex, ws_z, out);
}

// Round 9
// 205.713 us; speedup vs baseline: 1.0307x; 1.0307x over previous
//
#include <hip/hip_runtime.h>

// Problem constants (from reference)
#define DIM_IN   2048
#define FEAT     128
#define KP1      16385      // NCE_N + 1
#define NDATA    100000
#define BATCH    64
#define NBG      64         // bank rows per gemm block
#define NTG      ((NDATA + NBG - 1) / NBG)   // 1563
#define GCH      32         // k-chunks per (side,b) in gather kernel
#define LCH      8          // chunks in loss kernel

constexpr float NCE_T_INV = 1.0f / 0.07f;
constexpr float M_CONST   = 16384.0f / 100000.0f;   // NCE_N / N_DATA
constexpr float EPS_C     = 1e-7f;

typedef short bf16x8 __attribute__((ext_vector_type(8)));   // 8 bf16 = 4 VGPR
typedef float f32x4  __attribute__((ext_vector_type(4)));   // MFMA acc

// vplanes global layout (bytes), written by embed, DMA'd linearly by gemm:
//   plane(hi=0,lo=1)*34816 + side*17408 + anchor*272 + k*2
#define VP_PLANE 34816
#define VP_SIDE  17408
#define VP_ROW   272

// ---------------------------------------------------------------------------
// Kernel 1: h = l2norm(feat @ w.T + b), emitted as SPLIT-bf16 planes.
// 1024 threads (16 waves): verified round 5.
// Block 0 additionally zeroes z[128] and out.
// ---------------------------------------------------------------------------
__global__ void __launch_bounds__(1024) embed_kernel(
    const float* __restrict__ feat_s, const float* __restrict__ feat_t,
    const float* __restrict__ w_s, const float* __restrict__ b_s,
    const float* __restrict__ w_t, const float* __restrict__ b_t,
    char* __restrict__ vplanes, float* __restrict__ z_zero,
    float* __restrict__ out_zero)
{
    const int blk  = blockIdx.x;      // side*64 + b
    const int side = blk >> 6;
    const int b    = blk & 63;
    const float* feat = (side == 0 ? feat_s : feat_t) + (size_t)b * DIM_IN;
    const float* w    = (side == 0 ? w_s : w_t);
    const float* bias = (side == 0 ? b_s : b_t);

    __shared__ float sfeat[DIM_IN];
    __shared__ float pre[FEAT];
    __shared__ float wsum[2];

    const int t = threadIdx.x;
    if (blk == 0) {                   // fold the memsets into this launch
        if (t < 128) z_zero[t] = 0.f;
        else if (t == 128) out_zero[0] = 0.f;
    }
    {   // coalesced float4 stage of the feat row (8 KB, 512 float4)
        const float4* f4 = (const float4*)feat;
        float4* s4 = (float4*)sfeat;
        if (t < 512) s4[t] = f4[t];
    }
    __syncthreads();

    const int wv = t >> 6, ln = t & 63;   // 16 waves
    const float4* w4  = (const float4*)w;
    const float4* sf4 = (const float4*)sfeat;
#pragma unroll 2
    for (int i = 0; i < 8; ++i) {         // d = wv + 16*i: 8 iters/wave
        const int d = wv + i * 16;
        float s = 0.f;
#pragma unroll
        for (int seg = 0; seg < 8; ++seg) {  // 512 float4 per row / 64 lanes
            float4 a = w4[d * (DIM_IN / 4) + seg * 64 + ln];
            float4 f = sf4[seg * 64 + ln];
            s += a.x * f.x + a.y * f.y + a.z * f.z + a.w * f.w;
        }
#pragma unroll
        for (int o = 32; o > 0; o >>= 1) s += __shfl_xor(s, o, 64);
        if (ln == 0) pre[d] = s;
    }
    __syncthreads();

    if (t < 128) {
        float p = pre[t] + bias[t];
        pre[t] = p;
        float sq = p * p;
#pragma unroll
        for (int o = 32; o > 0; o >>= 1) sq += __shfl_xor(sq, o, 64);
        if ((t & 63) == 0) wsum[t >> 6] = sq;
    }
    __syncthreads();
    if (t < 128) {
        float inv_norm = 1.0f / sqrtf(wsum[0] + wsum[1]);
        float x = pre[t] * inv_norm;
        unsigned int u = __float_as_uint(x);
        unsigned short h = (unsigned short)(u >> 16);
        float hf = __uint_as_float(u & 0xffff0000u);
        float lr = x - hf;                         // exact in fp32
        unsigned short l = (unsigned short)(__float_as_uint(lr) >> 16);
        const size_t off = (size_t)side * VP_SIDE + (size_t)b * VP_ROW + t * 2;
        *(unsigned short*)(vplanes + off)            = h;
        *(unsigned short*)(vplanes + VP_PLANE + off) = l;
    }
}

// ---------------------------------------------------------------------------
// Kernel 2 (v3, ALL-DMA): E[sb][n] = exp(dot(bank[n], v[sb])/T).
// Round-8 post-mortem: VGPR=56 again -- asm memory-clobber did NOT pin the
// register burst; 3 rounds prove the compiler sinks any reg-staged B.
// global_load_lds is the one staging op it can't sink: fire-and-forget,
// zero VGPR. So: BOTH operands DMA'd before one barrier.
//   - B: 64 raw fp32 rows (32 KB, contiguous in global) DMA'd with
//     SOURCE-side XOR swizzle src^=(row&7)<<4 (rule: linear dest +
//     inverse-swz source + swz on read) -> chunk reads 2-way/free.
//   - A: vplanes 34 KB linear DMA (as r4-r8).
//   - LDS 67584 -> 2 blocks/CU; grid 3126 (~12 blocks/CU) de-phases
//     blocks so DMA streams cover other blocks' compute phases.
//   - 8 waves = 4 n-tiles x 2 m-halves; per wave per chunk: 2 LDS B reads,
//     convert to split hi/lo bf16, 4 A-frag reads, 6 MFMA.
//   - split-precision bf16x3: C = Ah*Bh + Al*Bh + Ah*Bl (absmax 0.0 r4-r8).
//   - C/D: col=lane&15 -> bank row n, row=(lane>>4)*4+reg -> anchor (m89).
// ---------------------------------------------------------------------------
__global__ void __launch_bounds__(512) gemm_exp_kernel(
    const float* __restrict__ mem_v1, const float* __restrict__ mem_v2,
    const char* __restrict__ vplanes, float* __restrict__ E)
{
    // LDS map (bytes):
    //   [0,17408)        A hi : anchor*272 + k*2
    //   [17408,34816)    A lo
    //   [34816,67584)    B    : row*512 + k*4 (source-swizzled)
    __shared__ __align__(16) char lds[67584];

    const int bx   = blockIdx.x;
    const int side = bx & 1;
    const int tile = bx >> 1;
    const int n0   = tile * NBG;
    const float* bank = (side == 0 ? mem_v2 : mem_v1);
    const int t  = threadIdx.x;
    const int wv = t >> 6, ln = t & 63;
    const int lm = ln & 15;           // MFMA lane index: n within 16-group
    const int kb = ln >> 4;           // MFMA k-block (0..3)
    const int ntile = wv & 3;         // n-tile (16 rows) this wave owns
    const int mhalf = wv >> 2;        // m-tiles {mhalf*2, mhalf*2+1}
    const int nloc  = ntile * 16 + lm;

    // ---- B DMA first (HBM, long latency): 32 segs x 1 KB ---------------
    {
        const size_t bmax = (size_t)NDATA * 512 - 16;   // clamp (last tile)
        const char* bbase = (const char*)bank;
        for (int s = wv; s < 32; s += 8) {
            const int o   = s * 1024 + ln * 16;         // linear LDS offset
            const int row = o >> 9;                     // tile-local row
            const int so  = (o & ~511) | ((o & 511) ^ ((row & 7) << 4));
            size_t g = (size_t)n0 * 512 + so;
            if (g > bmax) g = bmax;
            __builtin_amdgcn_global_load_lds(
                (const __attribute__((address_space(1))) void*)(bbase + g),
                (__attribute__((address_space(3))) void*)(lds + 34816 + s * 1024),
                16, 0, 0);
        }
    }
    // ---- A planes: linear DMA, 34 segs x 1 KB (L2-resident) ------------
    {
        const char* hbase = vplanes + (size_t)side * VP_SIDE;
        const char* lbase = vplanes + VP_PLANE + (size_t)side * VP_SIDE;
        for (int seg = wv; seg < 34; seg += 8) {
            const char* src = (seg < 17 ? hbase + seg * 1024
                                        : lbase + (seg - 17) * 1024) + ln * 16;
            __builtin_amdgcn_global_load_lds(
                (const __attribute__((address_space(1))) void*)src,
                (__attribute__((address_space(3))) void*)(lds + seg * 1024),
                16, 0, 0);
        }
    }

    f32x4 acc[2];
    acc[0] = (f32x4){0.f, 0.f, 0.f, 0.f};
    acc[1] = (f32x4){0.f, 0.f, 0.f, 0.f};

    __syncthreads();    // drains all DMA (vmcnt 0)

    const int sw = (nloc & 7) << 4;   // B read un-swizzle
#pragma unroll
    for (int c = 0; c < 4; ++c) {
        // B fragment from LDS: 32 B at row nloc, k = c*32 + kb*8
        const int bofs = nloc * 512 + c * 128 + kb * 32;
        const float4 f0 = *(const float4*)(lds + 34816 + ((bofs)      ^ sw));
        const float4 f1 = *(const float4*)(lds + 34816 + ((bofs + 16) ^ sw));
        const float xs[8] = {f0.x, f0.y, f0.z, f0.w, f1.x, f1.y, f1.z, f1.w};
        bf16x8 bh, bl;
#pragma unroll
        for (int j = 0; j < 8; ++j) {
            unsigned int u = __float_as_uint(xs[j]);
            bh[j] = (short)(u >> 16);
            float hf = __uint_as_float(u & 0xffff0000u);
            bl[j] = (short)(__float_as_uint(xs[j] - hf) >> 16);
        }
        // A fragments for this wave's 2 m-tiles
#pragma unroll
        for (int i = 0; i < 2; ++i) {
            const int mi = mhalf * 2 + i;
            bf16x8 ah = *(const bf16x8*)(lds + (mi * 16 + lm) * VP_ROW + c * 64 + kb * 16);
            bf16x8 al = *(const bf16x8*)(lds + 17408 + (mi * 16 + lm) * VP_ROW + c * 64 + kb * 16);
            acc[i] = __builtin_amdgcn_mfma_f32_16x16x32_bf16(ah, bh, acc[i], 0, 0, 0);
            acc[i] = __builtin_amdgcn_mfma_f32_16x16x32_bf16(al, bh, acc[i], 0, 0, 0);
            acc[i] = __builtin_amdgcn_mfma_f32_16x16x32_bf16(ah, bl, acc[i], 0, 0, 0);
        }
    }

    // epilogue: exp + store. col=lane&15 -> n, row=(lane>>4)*4+reg -> anchor.
    const int nn = n0 + nloc;
    if (nn < NDATA) {
#pragma unroll
        for (int i = 0; i < 2; ++i) {
            const int mi = mhalf * 2 + i;
#pragma unroll
            for (int jj = 0; jj < 4; ++jj) {
                const int anchor = mi * 16 + kb * 4 + jj;
                E[(size_t)(side * 64 + anchor) * NDATA + nn] =
                    __expf(acc[i][jj] * NCE_T_INV);
            }
        }
    }
}

// ---------------------------------------------------------------------------
// Kernel 3: gather ex = E[sb][idx[b,k]], store compact, accumulate Z[sb].
// GCH=32 (r8, neutral-kept). blk&127 = sb keeps chunks on one XCD.
// ---------------------------------------------------------------------------
__global__ void __launch_bounds__(256) gather_z_kernel(
    const int* __restrict__ sample_idx, const float* __restrict__ E,
    float* __restrict__ ex_out, float* __restrict__ z_out)
{
    const int blk   = blockIdx.x;
    const int chunk = blk >> 7;          // 0..GCH-1
    const int sb    = blk & 127;         // side*64 + b
    const int b     = sb & 63;
    const float* Eb = E + (size_t)sb * NDATA;

    float zp = 0.f;
    for (int k = chunk * 256 + threadIdx.x; k < KP1; k += GCH * 256) {
        const int idx = sample_idx[(size_t)b * KP1 + k];
        const float e = Eb[idx];
        ex_out[(size_t)sb * KP1 + k] = e;
        zp += e;
    }
#pragma unroll
    for (int o = 32; o > 0; o >>= 1) zp += __shfl_xor(zp, o, 64);
    __shared__ float zw[4];
    if ((threadIdx.x & 63) == 0) zw[threadIdx.x >> 6] = zp;
    __syncthreads();
    if (threadIdx.x == 0) atomicAdd(&z_out[sb], zw[0] + zw[1] + zw[2] + zw[3]);
}

// ---------------------------------------------------------------------------
// Kernel 4: loss. LCH=8 (r8, neutral-kept): 1024 blocks = 4 blocks/CU.
// Z summed in-kernel from the 64 per-sb partials of this side.
// ---------------------------------------------------------------------------
__global__ void __launch_bounds__(256) loss_kernel(
    const float* __restrict__ ex_in, const float* __restrict__ z_in,
    float* __restrict__ out)
{
    const int blk   = blockIdx.x;
    const int chunk = blk >> 7;          // 0..LCH-1
    const int sb    = blk & 127;
    const int side  = sb >> 6;

    __shared__ float zsh;
    if (threadIdx.x < 64) {
        float zv = z_in[side * 64 + threadIdx.x];
#pragma unroll
        for (int o = 32; o > 0; o >>= 1) zv += __shfl_xor(zv, o, 64);
        if (threadIdx.x == 0) zsh = zv;
    }
    __syncthreads();

    const float z  = zsh * ((float)NDATA / (64.0f * (float)KP1));
    const float rz = 1.0f / z;
    const float* ex = ex_in + (size_t)sb * KP1;

    float part = 0.f;
    for (int k = chunk * 256 + threadIdx.x; k < KP1; k += LCH * 256) {
        const float x = ex[k] * rz;
        if (k == 0) part += __logf(x / (x + M_CONST + EPS_C));
        else        part += __logf(M_CONST / (x + M_CONST + EPS_C));
    }
#pragma unroll
    for (int o = 32; o > 0; o >>= 1) part += __shfl_xor(part, o, 64);
    __shared__ float pw[4];
    if ((threadIdx.x & 63) == 0) pw[threadIdx.x >> 6] = part;
    __syncthreads();
    if (threadIdx.x == 0)
        atomicAdd(out, -(pw[0] + pw[1] + pw[2] + pw[3]) * (1.0f / 64.0f));
}

// ---------------------------------------------------------------------------
extern "C" void kernel_launch(void* const* d_in, const int* in_sizes, int n_in,
                              void* d_out, int out_size, void* d_ws, size_t ws_size,
                              hipStream_t stream)
{
    const float* feat_s     = (const float*)d_in[0];
    const float* feat_t     = (const float*)d_in[1];
    /* d_in[2] = idx, unused: sample_idx[:,0] already holds it */
    const int*   sample_idx = (const int*)  d_in[3];
    const float* w_s        = (const float*)d_in[4];
    const float* b_s        = (const float*)d_in[5];
    const float* w_t        = (const float*)d_in[6];
    const float* b_t        = (const float*)d_in[7];
    const float* mem_v1     = (const float*)d_in[8];
    const float* mem_v2     = (const float*)d_in[9];
    float* out = (float*)d_out;

    // Workspace layout:
    //   [z: 128 f32 = 512 B]
    //   [ex: 2*64*16385 f32 = 8.39 MB]   (gather-write -> loss-read)
    //   [vplanes: 69632 B, ALIASES ex]   (embed-write -> gemm-read; lifetimes
    //                                     disjoint: gemm ends before gather)
    //   [E: 128*100000 f32 = 51.2 MB]    (transposed: E[sb][n])
    char*  ws     = (char*)d_ws;
    float* ws_z   = (float*)ws;
    float* ws_ex  = (float*)(ws + 512);
    char*  ws_vp  = (char*)(ws + 512);   // alias of ex region
    float* ws_E   = (float*)(ws + 512 + (size_t)2 * BATCH * KP1 * sizeof(float));

    // z/out zeroing folded into embed_kernel block 0
    embed_kernel<<<2 * BATCH, 1024, 0, stream>>>(feat_s, feat_t, w_s, b_s, w_t, b_t,
                                                 ws_vp, ws_z, out);
    gemm_exp_kernel<<<2 * NTG, 512, 0, stream>>>(mem_v1, mem_v2, ws_vp, ws_E);
    gather_z_kernel<<<2 * BATCH * GCH, 256, 0, stream>>>(sample_idx, ws_E, ws_ex, ws_z);
    loss_kernel<<<2 * BATCH * LCH, 256, 0, stream>>>(ws_ex, ws_z, out);
}

// Round 10
// 203.983 us; speedup vs baseline: 1.0394x; 1.0085x over previous
//
#include <hip/hip_runtime.h>

// Problem constants (from reference)
#define DIM_IN   2048
#define FEAT     128
#define KP1      16385      // NCE_N + 1
#define NDATA    100000
#define BATCH    64
#define NBG      32         // bank rows per gemm block (exact: 32*3125=100000)
#define NTG      (NDATA / NBG)   // 3125
#define GCH      32         // k-chunks per b in gather kernel (sides fused)
#define LCH      8          // chunks in loss kernel (sides fused)

constexpr float NCE_T_INV = 1.0f / 0.07f;
constexpr float M_CONST   = 16384.0f / 100000.0f;   // NCE_N / N_DATA
constexpr float EPS_C     = 1e-7f;

typedef short bf16x8 __attribute__((ext_vector_type(8)));   // 8 bf16 = 4 VGPR
typedef float f32x4  __attribute__((ext_vector_type(4)));   // MFMA acc

// vplanes global layout (bytes), written by embed, DMA'd linearly by gemm:
//   plane(hi=0,lo=1)*34816 + side*17408 + anchor*272 + k*2
#define VP_PLANE 34816
#define VP_SIDE  17408
#define VP_ROW   272

// ---------------------------------------------------------------------------
// Kernel 1: h = l2norm(feat @ w.T + b), emitted as SPLIT-bf16 planes.
// 1024 threads (16 waves): verified round 5.
// Block 0 additionally zeroes z[128] and out.
// ---------------------------------------------------------------------------
__global__ void __launch_bounds__(1024) embed_kernel(
    const float* __restrict__ feat_s, const float* __restrict__ feat_t,
    const float* __restrict__ w_s, const float* __restrict__ b_s,
    const float* __restrict__ w_t, const float* __restrict__ b_t,
    char* __restrict__ vplanes, float* __restrict__ z_zero,
    float* __restrict__ out_zero)
{
    const int blk  = blockIdx.x;      // side*64 + b
    const int side = blk >> 6;
    const int b    = blk & 63;
    const float* feat = (side == 0 ? feat_s : feat_t) + (size_t)b * DIM_IN;
    const float* w    = (side == 0 ? w_s : w_t);
    const float* bias = (side == 0 ? b_s : b_t);

    __shared__ float sfeat[DIM_IN];
    __shared__ float pre[FEAT];
    __shared__ float wsum[2];

    const int t = threadIdx.x;
    if (blk == 0) {                   // fold the memsets into this launch
        if (t < 128) z_zero[t] = 0.f;
        else if (t == 128) out_zero[0] = 0.f;
    }
    {   // coalesced float4 stage of the feat row (8 KB, 512 float4)
        const float4* f4 = (const float4*)feat;
        float4* s4 = (float4*)sfeat;
        if (t < 512) s4[t] = f4[t];
    }
    __syncthreads();

    const int wv = t >> 6, ln = t & 63;   // 16 waves
    const float4* w4  = (const float4*)w;
    const float4* sf4 = (const float4*)sfeat;
#pragma unroll 2
    for (int i = 0; i < 8; ++i) {         // d = wv + 16*i: 8 iters/wave
        const int d = wv + i * 16;
        float s = 0.f;
#pragma unroll
        for (int seg = 0; seg < 8; ++seg) {  // 512 float4 per row / 64 lanes
            float4 a = w4[d * (DIM_IN / 4) + seg * 64 + ln];
            float4 f = sf4[seg * 64 + ln];
            s += a.x * f.x + a.y * f.y + a.z * f.z + a.w * f.w;
        }
#pragma unroll
        for (int o = 32; o > 0; o >>= 1) s += __shfl_xor(s, o, 64);
        if (ln == 0) pre[d] = s;
    }
    __syncthreads();

    if (t < 128) {
        float p = pre[t] + bias[t];
        pre[t] = p;
        float sq = p * p;
#pragma unroll
        for (int o = 32; o > 0; o >>= 1) sq += __shfl_xor(sq, o, 64);
        if ((t & 63) == 0) wsum[t >> 6] = sq;
    }
    __syncthreads();
    if (t < 128) {
        float inv_norm = 1.0f / sqrtf(wsum[0] + wsum[1]);
        float x = pre[t] * inv_norm;
        unsigned int u = __float_as_uint(x);
        unsigned short h = (unsigned short)(u >> 16);
        float hf = __uint_as_float(u & 0xffff0000u);
        float lr = x - hf;                         // exact in fp32
        unsigned short l = (unsigned short)(__float_as_uint(lr) >> 16);
        const size_t off = (size_t)side * VP_SIDE + (size_t)b * VP_ROW + t * 2;
        *(unsigned short*)(vplanes + off)            = h;
        *(unsigned short*)(vplanes + VP_PLANE + off) = l;
    }
}

// ---------------------------------------------------------------------------
// Kernel 2 (v4): E[sb][n] = exp(dot(bank[n], v[sb])/T).
// Round-9 post-mortem: all-DMA at 2 blocks/CU still 40 us / 2.5 TB/s --
// residency arithmetic is the limiter (2 x 64KB HBM work in flight per CU,
// full-drain barrier alternation). Bank-conflict chase DROPPED: b128 reads
// are at their ~4-way structural floor (quad = (kb*2)^(lm&7) covers 8 quads
// per 32-lane phase; m134's 85 B/cyc ceiling).
// FIX: NBG 64 -> 32, 256 threads: LDS 34816(A) + 16384(B) = 51200
// -> 3 blocks/CU, grid 6250 (~24 blocks/CU de-phasing).
//   - B: 16 KB raw fp32 rows DMA'd (source-XOR kept: harmless, read-side
//     un-swizzle verified r9 absmax 0.0).
//   - A: vplanes 34 KB linear DMA (L2-resident, all blocks share).
//   - 4 waves = 2 n-tiles x 2 m-pairs; acc[2]; 4 chunks x 6 MFMA.
//   - split-precision bf16x3: C = Ah*Bh + Al*Bh + Ah*Bl (absmax 0.0 r4-r9).
//   - C/D: col=lane&15 -> bank row n, row=(lane>>4)*4+reg -> anchor (m89).
// ---------------------------------------------------------------------------
__global__ void __launch_bounds__(256) gemm_exp_kernel(
    const float* __restrict__ mem_v1, const float* __restrict__ mem_v2,
    const char* __restrict__ vplanes, float* __restrict__ E)
{
    // LDS map (bytes):
    //   [0,17408)        A hi : anchor*272 + k*2
    //   [17408,34816)    A lo
    //   [34816,51200)    B    : row*512 + k*4 (source-swizzled)
    __shared__ __align__(16) char lds[51200];

    const int bx   = blockIdx.x;
    const int side = bx & 1;
    const int tile = bx >> 1;
    const int n0   = tile * NBG;
    const float* bank = (side == 0 ? mem_v2 : mem_v1);
    const int t  = threadIdx.x;
    const int wv = t >> 6, ln = t & 63;
    const int lm = ln & 15;           // MFMA lane index: n within 16-group
    const int kb = ln >> 4;           // MFMA k-block (0..3)
    const int ntile = wv & 1;         // n-tile (16 rows) this wave owns
    const int mpair = wv >> 1;        // m-tiles {mpair*2, mpair*2+1}
    const int nloc  = ntile * 16 + lm;

    // ---- B DMA first (HBM, long latency): 16 segs x 1 KB ---------------
    {
        const char* bbase = (const char*)bank;
        for (int s = wv; s < 16; s += 4) {
            const int o   = s * 1024 + ln * 16;         // linear LDS offset
            const int row = o >> 9;                     // tile-local row
            const int so  = (o & ~511) | ((o & 511) ^ ((row & 7) << 4));
            const size_t g = (size_t)n0 * 512 + so;     // exact: no tail
            __builtin_amdgcn_global_load_lds(
                (const __attribute__((address_space(1))) void*)(bbase + g),
                (__attribute__((address_space(3))) void*)(lds + 34816 + s * 1024),
                16, 0, 0);
        }
    }
    // ---- A planes: linear DMA, 34 segs x 1 KB (L2-resident) ------------
    {
        const char* hbase = vplanes + (size_t)side * VP_SIDE;
        const char* lbase = vplanes + VP_PLANE + (size_t)side * VP_SIDE;
        for (int seg = wv; seg < 34; seg += 4) {
            const char* src = (seg < 17 ? hbase + seg * 1024
                                        : lbase + (seg - 17) * 1024) + ln * 16;
            __builtin_amdgcn_global_load_lds(
                (const __attribute__((address_space(1))) void*)src,
                (__attribute__((address_space(3))) void*)(lds + seg * 1024),
                16, 0, 0);
        }
    }

    f32x4 acc[2];
    acc[0] = (f32x4){0.f, 0.f, 0.f, 0.f};
    acc[1] = (f32x4){0.f, 0.f, 0.f, 0.f};

    __syncthreads();    // drains all DMA (vmcnt 0)

    const int sw = (nloc & 7) << 4;   // B read un-swizzle
#pragma unroll
    for (int c = 0; c < 4; ++c) {
        // B fragment from LDS: 32 B at row nloc, k = c*32 + kb*8
        const int bofs = nloc * 512 + c * 128 + kb * 32;
        const float4 f0 = *(const float4*)(lds + 34816 + ((bofs)      ^ sw));
        const float4 f1 = *(const float4*)(lds + 34816 + ((bofs + 16) ^ sw));
        const float xs[8] = {f0.x, f0.y, f0.z, f0.w, f1.x, f1.y, f1.z, f1.w};
        bf16x8 bh, bl;
#pragma unroll
        for (int j = 0; j < 8; ++j) {
            unsigned int u = __float_as_uint(xs[j]);
            bh[j] = (short)(u >> 16);
            float hf = __uint_as_float(u & 0xffff0000u);
            bl[j] = (short)(__float_as_uint(xs[j] - hf) >> 16);
        }
        // A fragments for this wave's 2 m-tiles
#pragma unroll
        for (int i = 0; i < 2; ++i) {
            const int mi = mpair * 2 + i;
            bf16x8 ah = *(const bf16x8*)(lds + (mi * 16 + lm) * VP_ROW + c * 64 + kb * 16);
            bf16x8 al = *(const bf16x8*)(lds + 17408 + (mi * 16 + lm) * VP_ROW + c * 64 + kb * 16);
            acc[i] = __builtin_amdgcn_mfma_f32_16x16x32_bf16(ah, bh, acc[i], 0, 0, 0);
            acc[i] = __builtin_amdgcn_mfma_f32_16x16x32_bf16(al, bh, acc[i], 0, 0, 0);
            acc[i] = __builtin_amdgcn_mfma_f32_16x16x32_bf16(ah, bl, acc[i], 0, 0, 0);
        }
    }

    // epilogue: exp + store. col=lane&15 -> n, row=(lane>>4)*4+reg -> anchor.
    const int nn = n0 + nloc;
    if (nn < NDATA) {
#pragma unroll
        for (int i = 0; i < 2; ++i) {
            const int mi = mpair * 2 + i;
#pragma unroll
            for (int jj = 0; jj < 4; ++jj) {
                const int anchor = mi * 16 + kb * 4 + jj;
                E[(size_t)(side * 64 + anchor) * NDATA + nn] =
                    __expf(acc[i][jj] * NCE_T_INV);
            }
        }
    }
}

// ---------------------------------------------------------------------------
// Kernel 3: gather, SIDES FUSED (sample_idx shared by both sides): one idx
// load serves E[b] and E[64+b]; doubles per-thread MLP, halves idx traffic.
// 2048 blocks = 8/CU. blk&63 = b -> all chunks of b on one XCD (E-row L2).
// ---------------------------------------------------------------------------
__global__ void __launch_bounds__(256) gather_z_kernel(
    const int* __restrict__ sample_idx, const float* __restrict__ E,
    float* __restrict__ ex_out, float* __restrict__ z_out)
{
    const int blk   = blockIdx.x;
    const int chunk = blk >> 6;          // 0..GCH-1
    const int b     = blk & 63;
    const float* E0 = E + (size_t)b * NDATA;
    const float* E1 = E + (size_t)(64 + b) * NDATA;

    float zp0 = 0.f, zp1 = 0.f;
    for (int k = chunk * 256 + threadIdx.x; k < KP1; k += GCH * 256) {
        const int idx = sample_idx[(size_t)b * KP1 + k];
        const float e0 = E0[idx];
        const float e1 = E1[idx];
        ex_out[(size_t)b * KP1 + k]        = e0;
        ex_out[(size_t)(64 + b) * KP1 + k] = e1;
        zp0 += e0;
        zp1 += e1;
    }
#pragma unroll
    for (int o = 32; o > 0; o >>= 1) {
        zp0 += __shfl_xor(zp0, o, 64);
        zp1 += __shfl_xor(zp1, o, 64);
    }
    __shared__ float zw0[4], zw1[4];
    if ((threadIdx.x & 63) == 0) {
        zw0[threadIdx.x >> 6] = zp0;
        zw1[threadIdx.x >> 6] = zp1;
    }
    __syncthreads();
    if (threadIdx.x == 0) {
        atomicAdd(&z_out[b],      zw0[0] + zw0[1] + zw0[2] + zw0[3]);
        atomicAdd(&z_out[64 + b], zw1[0] + zw1[1] + zw1[2] + zw1[3]);
    }
}

// ---------------------------------------------------------------------------
// Kernel 4: loss, SIDES FUSED: one pass reads both ex rows of b.
// 512 blocks (LCH=8 x 64 b).
// ---------------------------------------------------------------------------
__global__ void __launch_bounds__(256) loss_kernel(
    const float* __restrict__ ex_in, const float* __restrict__ z_in,
    float* __restrict__ out)
{
    const int blk   = blockIdx.x;
    const int chunk = blk >> 6;          // 0..LCH-1
    const int b     = blk & 63;

    __shared__ float zsh[2];
    if (threadIdx.x < 128) {             // wave0 -> side0, wave1 -> side1
        float zv = z_in[threadIdx.x];
#pragma unroll
        for (int o = 32; o > 0; o >>= 1) zv += __shfl_xor(zv, o, 64);
        if ((threadIdx.x & 63) == 0) zsh[threadIdx.x >> 6] = zv;
    }
    __syncthreads();

    const float scale = (float)NDATA / (64.0f * (float)KP1);
    const float rz0 = 1.0f / (zsh[0] * scale);
    const float rz1 = 1.0f / (zsh[1] * scale);
    const float* ex0 = ex_in + (size_t)b * KP1;
    const float* ex1 = ex_in + (size_t)(64 + b) * KP1;

    float part = 0.f;
    for (int k = chunk * 256 + threadIdx.x; k < KP1; k += LCH * 256) {
        const float x0 = ex0[k] * rz0;
        const float x1 = ex1[k] * rz1;
        if (k == 0) {
            part += __logf(x0 / (x0 + M_CONST + EPS_C));
            part += __logf(x1 / (x1 + M_CONST + EPS_C));
        } else {
            part += __logf(M_CONST / (x0 + M_CONST + EPS_C));
            part += __logf(M_CONST / (x1 + M_CONST + EPS_C));
        }
    }
#pragma unroll
    for (int o = 32; o > 0; o >>= 1) part += __shfl_xor(part, o, 64);
    __shared__ float pw[4];
    if ((threadIdx.x & 63) == 0) pw[threadIdx.x >> 6] = part;
    __syncthreads();
    if (threadIdx.x == 0)
        atomicAdd(out, -(pw[0] + pw[1] + pw[2] + pw[3]) * (1.0f / 64.0f));
}

// ---------------------------------------------------------------------------
extern "C" void kernel_launch(void* const* d_in, const int* in_sizes, int n_in,
                              void* d_out, int out_size, void* d_ws, size_t ws_size,
                              hipStream_t stream)
{
    const float* feat_s     = (const float*)d_in[0];
    const float* feat_t     = (const float*)d_in[1];
    /* d_in[2] = idx, unused: sample_idx[:,0] already holds it */
    const int*   sample_idx = (const int*)  d_in[3];
    const float* w_s        = (const float*)d_in[4];
    const float* b_s        = (const float*)d_in[5];
    const float* w_t        = (const float*)d_in[6];
    const float* b_t        = (const float*)d_in[7];
    const float* mem_v1     = (const float*)d_in[8];
    const float* mem_v2     = (const float*)d_in[9];
    float* out = (float*)d_out;

    // Workspace layout:
    //   [z: 128 f32 = 512 B]
    //   [ex: 2*64*16385 f32 = 8.39 MB]   (gather-write -> loss-read)
    //   [vplanes: 69632 B, ALIASES ex]   (embed-write -> gemm-read; lifetimes
    //                                     disjoint: gemm ends before gather)
    //   [E: 128*100000 f32 = 51.2 MB]    (transposed: E[sb][n])
    char*  ws     = (char*)d_ws;
    float* ws_z   = (float*)ws;
    float* ws_ex  = (float*)(ws + 512);
    char*  ws_vp  = (char*)(ws + 512);   // alias of ex region
    float* ws_E   = (float*)(ws + 512 + (size_t)2 * BATCH * KP1 * sizeof(float));

    // z/out zeroing folded into embed_kernel block 0
    embed_kernel<<<2 * BATCH, 1024, 0, stream>>>(feat_s, feat_t, w_s, b_s, w_t, b_t,
                                                 ws_vp, ws_z, out);
    gemm_exp_kernel<<<2 * NTG, 256, 0, stream>>>(mem_v1, mem_v2, ws_vp, ws_E);
    gather_z_kernel<<<BATCH * GCH, 256, 0, stream>>>(sample_idx, ws_E, ws_ex, ws_z);
    loss_kernel<<<BATCH * LCH, 256, 0, stream>>>(ws_ex, ws_z, out);
}

// Round 11
// 197.284 us; speedup vs baseline: 1.0747x; 1.0340x over previous
//
#include <hip/hip_runtime.h>

// Problem constants (from reference)
#define DIM_IN   2048
#define FEAT     128
#define KP1      16385      // NCE_N + 1
#define NDATA    100000
#define BATCH    64
#define NBG      32         // bank rows per gemm tile
#define TPB      8          // tiles per block (persistent loop)
#define RPB      (NBG * TPB)                  // 256 rows per block
#define NBLK2    ((NDATA + RPB - 1) / RPB)    // 391
#define GCH      8          // chunks per b in gather kernel (int4 groups)
#define LCH      4          // chunks in loss kernel
#define EXR      16388      // padded ex row (16 B-aligned float4 groups)

constexpr float NCE_T_INV = 1.0f / 0.07f;
constexpr float M_CONST   = 16384.0f / 100000.0f;   // NCE_N / N_DATA
constexpr float EPS_C     = 1e-7f;

typedef short bf16x8 __attribute__((ext_vector_type(8)));   // 8 bf16 = 4 VGPR
typedef float f32x4  __attribute__((ext_vector_type(4)));   // MFMA acc

// vplanes global layout (bytes), written by embed, DMA'd linearly by gemm:
//   plane(hi=0,lo=1)*34816 + side*17408 + anchor*272 + k*2
#define VP_PLANE 34816
#define VP_SIDE  17408
#define VP_ROW   272

// ---------------------------------------------------------------------------
// Kernel 1: h = l2norm(feat @ w.T + b), emitted as SPLIT-bf16 planes.
// 1024 threads (16 waves): verified round 5. Unchanged this round.
// Block 0 additionally zeroes z[128] and out.
// ---------------------------------------------------------------------------
__global__ void __launch_bounds__(1024) embed_kernel(
    const float* __restrict__ feat_s, const float* __restrict__ feat_t,
    const float* __restrict__ w_s, const float* __restrict__ b_s,
    const float* __restrict__ w_t, const float* __restrict__ b_t,
    char* __restrict__ vplanes, float* __restrict__ z_zero,
    float* __restrict__ out_zero)
{
    const int blk  = blockIdx.x;      // side*64 + b
    const int side = blk >> 6;
    const int b    = blk & 63;
    const float* feat = (side == 0 ? feat_s : feat_t) + (size_t)b * DIM_IN;
    const float* w    = (side == 0 ? w_s : w_t);
    const float* bias = (side == 0 ? b_s : b_t);

    __shared__ float sfeat[DIM_IN];
    __shared__ float pre[FEAT];
    __shared__ float wsum[2];

    const int t = threadIdx.x;
    if (blk == 0) {                   // fold the memsets into this launch
        if (t < 128) z_zero[t] = 0.f;
        else if (t == 128) out_zero[0] = 0.f;
    }
    {   // coalesced float4 stage of the feat row (8 KB, 512 float4)
        const float4* f4 = (const float4*)feat;
        float4* s4 = (float4*)sfeat;
        if (t < 512) s4[t] = f4[t];
    }
    __syncthreads();

    const int wv = t >> 6, ln = t & 63;   // 16 waves
    const float4* w4  = (const float4*)w;
    const float4* sf4 = (const float4*)sfeat;
#pragma unroll 2
    for (int i = 0; i < 8; ++i) {         // d = wv + 16*i: 8 iters/wave
        const int d = wv + i * 16;
        float s = 0.f;
#pragma unroll
        for (int seg = 0; seg < 8; ++seg) {  // 512 float4 per row / 64 lanes
            float4 a = w4[d * (DIM_IN / 4) + seg * 64 + ln];
            float4 f = sf4[seg * 64 + ln];
            s += a.x * f.x + a.y * f.y + a.z * f.z + a.w * f.w;
        }
#pragma unroll
        for (int o = 32; o > 0; o >>= 1) s += __shfl_xor(s, o, 64);
        if (ln == 0) pre[d] = s;
    }
    __syncthreads();

    if (t < 128) {
        float p = pre[t] + bias[t];
        pre[t] = p;
        float sq = p * p;
#pragma unroll
        for (int o = 32; o > 0; o >>= 1) sq += __shfl_xor(sq, o, 64);
        if ((t & 63) == 0) wsum[t >> 6] = sq;
    }
    __syncthreads();
    if (t < 128) {
        float inv_norm = 1.0f / sqrtf(wsum[0] + wsum[1]);
        float x = pre[t] * inv_norm;
        unsigned int u = __float_as_uint(x);
        unsigned short h = (unsigned short)(u >> 16);
        float hf = __uint_as_float(u & 0xffff0000u);
        float lr = x - hf;                         // exact in fp32
        unsigned short l = (unsigned short)(__float_as_uint(lr) >> 16);
        const size_t off = (size_t)side * VP_SIDE + (size_t)b * VP_ROW + t * 2;
        *(unsigned short*)(vplanes + off)            = h;
        *(unsigned short*)(vplanes + VP_PLANE + off) = l;
    }
}

// ---------------------------------------------------------------------------
// Kernel 2 (v5, PERSISTENT + COUNTED VMCNT): E[sb][n] = exp(dot/T).
// Rounds 6-10 post-mortem: five structures, all ~41 us / 2.5 TB/s. The
// invariant: __syncthreads (= s_waitcnt vmcnt(0) + s_barrier) drains ALL
// in-flight HBM traffic once per B-tile, and short-lived blocks never
// sustain queue depth. This is the documented m97 barrier-drain stall; the
// escape is T3/T4: counted vmcnt + raw s_barrier (m201 pattern, plain HIP).
// Structure: block owns TPB=8 consecutive 32-row tiles.
//   - A (34 KB) DMA'd ONCE per block (8x less A L2 traffic than r10).
//   - B double-buffered 2x16 KB; per tile per wave 4 gload_lds.
//   - loop t: waitcnt vmcnt(8) [8 = newer store instrs; in-order retire
//     => the 4 older DMA(t) retired] -> raw s_barrier -> issue DMA(t+1)
//     into the buffer all waves provably left -> compute t + stores.
//     DMA(t+1) stays in flight across compute(t): HBM never idles.
//   - asm "memory" clobber orders the ds_reads after the wait (consumers
//     are memory ops -> clobber suffices; rule-18 is about reg-only MFMA).
// LDS 67584 -> 2 blocks/CU. split-bf16x3 math unchanged (absmax 0.0 r4-r10).
// ---------------------------------------------------------------------------
__global__ void __launch_bounds__(256) gemm_exp_kernel(
    const float* __restrict__ mem_v1, const float* __restrict__ mem_v2,
    const char* __restrict__ vplanes, float* __restrict__ E)
{
    // LDS map (bytes):
    //   [0,17408)        A hi : anchor*272 + k*2
    //   [17408,34816)    A lo
    //   [34816,+16384)   B buf0 : row*512 + k*4 (source-swizzled)
    //   [51200,+16384)   B buf1
    __shared__ __align__(16) char lds[67584];

    const int bx   = blockIdx.x;
    const int side = bx & 1;
    const int blk0 = (bx >> 1) * RPB;     // first bank row of this block
    const float* bank = (side == 0 ? mem_v2 : mem_v1);
    const int t  = threadIdx.x;
    const int wv = t >> 6, ln = t & 63;
    const int lm = ln & 15;           // MFMA lane index: n within 16-group
    const int kb = ln >> 4;           // MFMA k-block (0..3)
    const int ntile = wv & 1;         // n-subtile (16 rows) this wave owns
    const int mpair = wv >> 1;        // m-tiles {mpair*2, mpair*2+1}
    const int nloc  = ntile * 16 + lm;

    const size_t bmax = (size_t)NDATA * 512 - 16;
    const char* bbase = (const char*)bank;

    // ---- A planes: linear DMA once, 34 segs x 1 KB (L2-resident) -------
    {
        const char* hbase = vplanes + (size_t)side * VP_SIDE;
        const char* lbase = vplanes + VP_PLANE + (size_t)side * VP_SIDE;
        for (int seg = wv; seg < 34; seg += 4) {
            const char* src = (seg < 17 ? hbase + seg * 1024
                                        : lbase + (seg - 17) * 1024) + ln * 16;
            __builtin_amdgcn_global_load_lds(
                (const __attribute__((address_space(1))) void*)src,
                (__attribute__((address_space(3))) void*)(lds + seg * 1024),
                16, 0, 0);
        }
    }
    // ---- B tile 0 into buf 0: 16 segs x 1 KB, 4 per wave ---------------
#pragma unroll
    for (int s0 = 0; s0 < 4; ++s0) {
        const int s   = wv + s0 * 4;
        const int o   = s * 1024 + ln * 16;
        const int row = o >> 9;
        const int so  = (o & ~511) | ((o & 511) ^ ((row & 7) << 4));
        size_t g = (size_t)blk0 * 512 + so;
        if (g > bmax) g = bmax;
        __builtin_amdgcn_global_load_lds(
            (const __attribute__((address_space(1))) void*)(bbase + g),
            (__attribute__((address_space(3))) void*)(lds + 34816 + s * 1024),
            16, 0, 0);
    }

    const int sw = (nloc & 7) << 4;   // B read un-swizzle

#pragma unroll 1
    for (int tt = 0; tt < TPB; ++tt) {
        // wait for tile tt's B (and, at tt=0, A): in-order vm retire means
        // vmcnt(8) leaves only the 8 newer store instrs outstanding.
        if (tt == 0) asm volatile("s_waitcnt vmcnt(0)" ::: "memory");
        else         asm volatile("s_waitcnt vmcnt(8)" ::: "memory");
        __builtin_amdgcn_s_barrier();

        // issue tile tt+1 into the other buffer (all waves left it: they
        // passed the barrier after computing tile tt-1).
        if (tt + 1 < TPB) {
            const int n1 = blk0 + (tt + 1) * NBG;
            const int bb = ((tt + 1) & 1) * 16384;
#pragma unroll
            for (int s0 = 0; s0 < 4; ++s0) {
                const int s   = wv + s0 * 4;
                const int o   = s * 1024 + ln * 16;
                const int row = o >> 9;
                const int so  = (o & ~511) | ((o & 511) ^ ((row & 7) << 4));
                size_t g = (size_t)n1 * 512 + so;
                if (g > bmax) g = bmax;
                __builtin_amdgcn_global_load_lds(
                    (const __attribute__((address_space(1))) void*)(bbase + g),
                    (__attribute__((address_space(3))) void*)(lds + 34816 + bb + s * 1024),
                    16, 0, 0);
            }
        }

        // ---- compute tile tt from buf[tt&1] ----------------------------
        const char* B = lds + 34816 + (tt & 1) * 16384;
        f32x4 acc[2];
        acc[0] = (f32x4){0.f, 0.f, 0.f, 0.f};
        acc[1] = (f32x4){0.f, 0.f, 0.f, 0.f};
#pragma unroll
        for (int c = 0; c < 4; ++c) {
            const int bofs = nloc * 512 + c * 128 + kb * 32;
            const float4 f0 = *(const float4*)(B + ((bofs)      ^ sw));
            const float4 f1 = *(const float4*)(B + ((bofs + 16) ^ sw));
            const float xs[8] = {f0.x, f0.y, f0.z, f0.w, f1.x, f1.y, f1.z, f1.w};
            bf16x8 bh, bl;
#pragma unroll
            for (int j = 0; j < 8; ++j) {
                unsigned int u = __float_as_uint(xs[j]);
                bh[j] = (short)(u >> 16);
                float hf = __uint_as_float(u & 0xffff0000u);
                bl[j] = (short)(__float_as_uint(xs[j] - hf) >> 16);
            }
#pragma unroll
            for (int i = 0; i < 2; ++i) {
                const int mi = mpair * 2 + i;
                bf16x8 ah = *(const bf16x8*)(lds + (mi * 16 + lm) * VP_ROW + c * 64 + kb * 16);
                bf16x8 al = *(const bf16x8*)(lds + 17408 + (mi * 16 + lm) * VP_ROW + c * 64 + kb * 16);
                acc[i] = __builtin_amdgcn_mfma_f32_16x16x32_bf16(ah, bh, acc[i], 0, 0, 0);
                acc[i] = __builtin_amdgcn_mfma_f32_16x16x32_bf16(al, bh, acc[i], 0, 0, 0);
                acc[i] = __builtin_amdgcn_mfma_f32_16x16x32_bf16(ah, bl, acc[i], 0, 0, 0);
            }
        }

        // epilogue: exp + store (8 store instrs -> the vmcnt(8) above).
        const int nn = blk0 + tt * NBG + nloc;
        if (nn < NDATA) {
#pragma unroll
            for (int i = 0; i < 2; ++i) {
                const int mi = mpair * 2 + i;
#pragma unroll
                for (int jj = 0; jj < 4; ++jj) {
                    const int anchor = mi * 16 + kb * 4 + jj;
                    E[(size_t)(side * 64 + anchor) * NDATA + nn] =
                        __expf(acc[i][jj] * NCE_T_INV);
                }
            }
        }
    }
}

// ---------------------------------------------------------------------------
// Kernel 3 (v2): gather, sides fused, 4 idx + 8 independent random E reads
// per iteration (4x MLP), float4 ex stores via EXR=16388 row padding.
// Grid 512 (GCH=8 x 64 b); blk&63=b keeps b's chunks on one XCD.
// ---------------------------------------------------------------------------
__global__ void __launch_bounds__(256) gather_z_kernel(
    const int* __restrict__ sample_idx, const float* __restrict__ E,
    float* __restrict__ ex_out, float* __restrict__ z_out)
{
    const int blk   = blockIdx.x;
    const int chunk = blk >> 6;          // 0..GCH-1
    const int b     = blk & 63;
    const int* sidx = sample_idx + (size_t)b * KP1;
    const float* E0 = E + (size_t)b * NDATA;
    const float* E1 = E + (size_t)(64 + b) * NDATA;

    float zp0 = 0.f, zp1 = 0.f;
    for (int g = chunk * 256 + threadIdx.x; g < 4096; g += GCH * 256) {
        const int i0 = sidx[g * 4 + 0];
        const int i1 = sidx[g * 4 + 1];
        const int i2 = sidx[g * 4 + 2];
        const int i3 = sidx[g * 4 + 3];
        float4 v0, v1;
        v0.x = E0[i0]; v0.y = E0[i1]; v0.z = E0[i2]; v0.w = E0[i3];
        v1.x = E1[i0]; v1.y = E1[i1]; v1.z = E1[i2]; v1.w = E1[i3];
        *(float4*)&ex_out[(size_t)b * EXR + g * 4]        = v0;
        *(float4*)&ex_out[(size_t)(64 + b) * EXR + g * 4] = v1;
        zp0 += v0.x + v0.y + v0.z + v0.w;
        zp1 += v1.x + v1.y + v1.z + v1.w;
    }
    if (chunk == 0 && threadIdx.x == 0) {   // tail k = 16384
        const int it = sidx[16384];
        const float ta = E0[it], tb = E1[it];
        ex_out[(size_t)b * EXR + 16384]        = ta;
        ex_out[(size_t)(64 + b) * EXR + 16384] = tb;
        zp0 += ta; zp1 += tb;
    }
#pragma unroll
    for (int o = 32; o > 0; o >>= 1) {
        zp0 += __shfl_xor(zp0, o, 64);
        zp1 += __shfl_xor(zp1, o, 64);
    }
    __shared__ float zw0[4], zw1[4];
    if ((threadIdx.x & 63) == 0) {
        zw0[threadIdx.x >> 6] = zp0;
        zw1[threadIdx.x >> 6] = zp1;
    }
    __syncthreads();
    if (threadIdx.x == 0) {
        atomicAdd(&z_out[b],      zw0[0] + zw0[1] + zw0[2] + zw0[3]);
        atomicAdd(&z_out[64 + b], zw1[0] + zw1[1] + zw1[2] + zw1[3]);
    }
}

// ---------------------------------------------------------------------------
// Kernel 4 (v2): loss, sides fused, float4 reads of padded ex rows.
// Grid 256 (LCH=4 x 64 b).
// ---------------------------------------------------------------------------
__global__ void __launch_bounds__(256) loss_kernel(
    const float* __restrict__ ex_in, const float* __restrict__ z_in,
    float* __restrict__ out)
{
    const int blk   = blockIdx.x;
    const int chunk = blk >> 6;          // 0..LCH-1
    const int b     = blk & 63;

    __shared__ float zsh[2];
    if (threadIdx.x < 128) {             // wave0 -> side0, wave1 -> side1
        float zv = z_in[threadIdx.x];
#pragma unroll
        for (int o = 32; o > 0; o >>= 1) zv += __shfl_xor(zv, o, 64);
        if ((threadIdx.x & 63) == 0) zsh[threadIdx.x >> 6] = zv;
    }
    __syncthreads();

    const float scale = (float)NDATA / (64.0f * (float)KP1);
    const float rz0 = 1.0f / (zsh[0] * scale);
    const float rz1 = 1.0f / (zsh[1] * scale);
    const float* ex0 = ex_in + (size_t)b * EXR;
    const float* ex1 = ex_in + (size_t)(64 + b) * EXR;

    float part = 0.f;
    for (int g = chunk * 256 + threadIdx.x; g < 4097; g += LCH * 256) {
        const float4 a0 = *(const float4*)&ex0[g * 4];
        const float4 a1 = *(const float4*)&ex1[g * 4];
        const float e0[4] = {a0.x, a0.y, a0.z, a0.w};
        const float e1[4] = {a1.x, a1.y, a1.z, a1.w};
#pragma unroll
        for (int j = 0; j < 4; ++j) {
            const int k = g * 4 + j;
            if (k >= KP1) break;
            const float x0 = e0[j] * rz0;
            const float x1 = e1[j] * rz1;
            if (k == 0) {
                part += __logf(x0 / (x0 + M_CONST + EPS_C));
                part += __logf(x1 / (x1 + M_CONST + EPS_C));
            } else {
                part += __logf(M_CONST / (x0 + M_CONST + EPS_C));
                part += __logf(M_CONST / (x1 + M_CONST + EPS_C));
            }
        }
    }
#pragma unroll
    for (int o = 32; o > 0; o >>= 1) part += __shfl_xor(part, o, 64);
    __shared__ float pw[4];
    if ((threadIdx.x & 63) == 0) pw[threadIdx.x >> 6] = part;
    __syncthreads();
    if (threadIdx.x == 0)
        atomicAdd(out, -(pw[0] + pw[1] + pw[2] + pw[3]) * (1.0f / 64.0f));
}

// ---------------------------------------------------------------------------
extern "C" void kernel_launch(void* const* d_in, const int* in_sizes, int n_in,
                              void* d_out, int out_size, void* d_ws, size_t ws_size,
                              hipStream_t stream)
{
    const float* feat_s     = (const float*)d_in[0];
    const float* feat_t     = (const float*)d_in[1];
    /* d_in[2] = idx, unused: sample_idx[:,0] already holds it */
    const int*   sample_idx = (const int*)  d_in[3];
    const float* w_s        = (const float*)d_in[4];
    const float* b_s        = (const float*)d_in[5];
    const float* w_t        = (const float*)d_in[6];
    const float* b_t        = (const float*)d_in[7];
    const float* mem_v1     = (const float*)d_in[8];
    const float* mem_v2     = (const float*)d_in[9];
    float* out = (float*)d_out;

    // Workspace layout:
    //   [z: 128 f32 = 512 B]
    //   [ex: 128*EXR f32 = 8.39 MB]      (gather-write -> loss-read, padded)
    //   [vplanes: 69632 B, ALIASES ex]   (embed-write -> gemm-read; lifetimes
    //                                     disjoint: gemm ends before gather)
    //   [E: 128*100000 f32 = 51.2 MB]    (transposed: E[sb][n])
    char*  ws     = (char*)d_ws;
    float* ws_z   = (float*)ws;
    float* ws_ex  = (float*)(ws + 512);
    char*  ws_vp  = (char*)(ws + 512);   // alias of ex region
    float* ws_E   = (float*)(ws + 512 + (size_t)128 * EXR * sizeof(float));

    // z/out zeroing folded into embed_kernel block 0
    embed_kernel<<<2 * BATCH, 1024, 0, stream>>>(feat_s, feat_t, w_s, b_s, w_t, b_t,
                                                 ws_vp, ws_z, out);
    gemm_exp_kernel<<<2 * NBLK2, 256, 0, stream>>>(mem_v1, mem_v2, ws_vp, ws_E);
    gather_z_kernel<<<BATCH * GCH, 256, 0, stream>>>(sample_idx, ws_E, ws_ex, ws_z);
    loss_kernel<<<BATCH * LCH, 256, 0, stream>>>(ws_ex, ws_z, out);
}